// Round 11
// baseline (220.345 us; speedup 1.0000x reference)
//
#include <hip/hip_runtime.h>
#include <hip/hip_bf16.h>

typedef unsigned short u16;
typedef short bf16x8 __attribute__((ext_vector_type(8)));
typedef float f32x4 __attribute__((ext_vector_type(4)));

// 2^x via raw v_exp_f32 (NOT __exp2f: glibc math.h declares a host __exp2f,
// which collides in hipcc's merged TU)
#define EXP2(x) __builtin_amdgcn_exp2f(x)

static __device__ __forceinline__ u16 f2bf(float f) {
  union { float f; unsigned u; } a; a.f = f;
  unsigned r = a.u + 0x7fffu + ((a.u >> 16) & 1u);  // RNE
  return (u16)(r >> 16);
}

static __device__ __forceinline__ unsigned pkbf(float a, float b) {
  union { __hip_bfloat162 h; unsigned u; } c;
  c.h = __float22bfloat162_rn(make_float2(a, b));
  return c.u;  // low 16 = a, high 16 = b
}

static __device__ __forceinline__ bf16x8 as_bf(int4 v) {
  union { int4 i; bf16x8 b; } u; u.i = v; return u.b;
}

// async global->LDS, 16B per lane; LDS dest = wave-uniform base + lane*16
#define GLDS16(g, l)                                         \
  __builtin_amdgcn_global_load_lds(                          \
      (const __attribute__((address_space(1))) void*)(g),    \
      (__attribute__((address_space(3))) void*)(l), 16, 0, 0)

// ---------------- fused prep: x cast + 4 weight transposes ----------------
// blocks [0,1024): cvt x (fp32->bf16, 8 elems/thread)
// blocks [1024,1280): transpose_w for Wq/Wk/Wv/Wu (64 blocks each)
__global__ __launch_bounds__(256) void prep(
    const float* __restrict__ x, u16* __restrict__ Xb,
    const float* __restrict__ Wq, u16* __restrict__ Wqt,
    const float* __restrict__ Wk, u16* __restrict__ Wkt,
    const float* __restrict__ Wv, u16* __restrict__ Wvt,
    const float* __restrict__ Wu, u16* __restrict__ Wut) {
  const int bid = blockIdx.x, tid = threadIdx.x;
  if (bid < 1024) {
    int i = bid * 256 + tid;
    const float4* p = (const float4*)x + (size_t)i * 2;
    float4 a = p[0], b = p[1];
    union { unsigned s[4]; int4 v; } u2;
    u2.s[0] = pkbf(a.x, a.y); u2.s[1] = pkbf(a.z, a.w);
    u2.s[2] = pkbf(b.x, b.y); u2.s[3] = pkbf(b.z, b.w);
    ((int4*)Xb)[i] = u2.v;
    return;
  }
  const int which = (bid - 1024) >> 6;
  const float* in; u16* out; int R, C;
  if (which == 0)      { in = Wq; out = Wqt; R = 256;  C = 2048; }
  else if (which == 1) { in = Wk; out = Wkt; R = 256;  C = 2048; }
  else if (which == 2) { in = Wv; out = Wvt; R = 256;  C = 2048; }
  else                 { in = Wu; out = Wut; R = 2048; C = 256;  }
  int T = ((bid - 1024) & 63) * 256 + tid;
  int c = T % C;
  int r0 = (T / C) * 32;
  __align__(16) u16 tmp[32];
#pragma unroll
  for (int j = 0; j < 32; ++j) tmp[j] = f2bf(in[(size_t)(r0 + j) * C + c]);
#pragma unroll
  for (int q = 0; q < 4; ++q)
    *(int4*)(out + (size_t)c * R + r0 + q * 8) = *(int4*)&tmp[q * 8];
}

// ---------------- fused QKV GEMM (M=8192,N=2048,K=256, 128x256 / 8 waves) ------
// Round-10: BM=128 x BN=256 with 512 threads (8 waves, 2m x 4n), per-wave tile
// kept at the verified 64x64 (acc = 64 VGPR). This takes r6's widening benefit
// (half the blocks -> half the prologue/epilogue count; A staged 24x not 48x;
// per-CU staging per k-step -25%) while fixing r6's attributed failure causes:
// per-wave VGPR is unchanged (~110 -> 16 waves/CU -> 2 blocks of 8 waves
// co-resident, invariant preserved; LDS 48 KB also allows 2) and the V^T
// epilogue phases run with 8 waves. All swizzle algebra identical to the
// verified 128x128 kernel (chunk = 8 rows x 64 cols, u^(r&7) involution both
// sides, read slot (kk*4+quad)^(lq&7); r = lq mod 16 so r&7 = lq&7 holds).
// z=0 -> Q (row-major bf16), z=1 -> K (row-major), z=2 -> V^T directly.
__global__ __launch_bounds__(512) void gemm_qkv(const u16* __restrict__ A,
                                                const u16* __restrict__ Wt,
                                                const float* __restrict__ bq,
                                                const float* __restrict__ bk,
                                                const float* __restrict__ bv,
                                                u16* __restrict__ Qw,
                                                u16* __restrict__ Kw,
                                                u16* __restrict__ Vt) {
  constexpr int BM = 128, BN = 256, BK = 64;
  __shared__ int4 smem4[3072];  // 48 KB: As(16K) | Bs(32K); reused for transpose
  int4* As4 = smem4;
  int4* Bs4 = smem4 + 1024;
  const int tid = threadIdx.x;
  const int w = tid >> 6, lane = tid & 63, lq = lane & 15, quad = lane >> 4;
  const int wm = w >> 2, wn = w & 3;  // 2m x 4n wave grid, 64x64 each
  const int m0 = blockIdx.y * BM, n0 = blockIdx.x * BN;
  const int z = blockIdx.z;

  const u16* Btz = Wt + (size_t)z * 2048 * 256;
  const float* bias = (z == 0) ? bq : (z == 1 ? bk : bv);

  const int srow = lane >> 3;
  const int scb = (lane & 7) ^ ((lane >> 3) & 7);

  f32x4 acc[4][4];
#pragma unroll
  for (int mi = 0; mi < 4; ++mi)
#pragma unroll
    for (int ni = 0; ni < 4; ++ni) {
      f32x4 z4 = {0.f, 0.f, 0.f, 0.f};
      acc[mi][ni] = z4;
    }

  for (int k0 = 0; k0 < 256; k0 += BK) {
    __syncthreads();
    // As: 16 chunks (1 KB = 8 rows x 64 cols), wave w stages chunks w*2+it
#pragma unroll
    for (int it = 0; it < 2; ++it) {
      int r = (w * 2 + it) * 8 + srow;
      GLDS16(A + (size_t)(m0 + r) * 256 + k0 + scb * 8,
             (char*)As4 + (w * 2 + it) * 1024);
    }
    // Bs: 32 chunks, wave w stages chunks w*4+it
#pragma unroll
    for (int it = 0; it < 4; ++it) {
      int r = (w * 4 + it) * 8 + srow;
      GLDS16(Btz + (size_t)(n0 + r) * 256 + k0 + scb * 8,
             (char*)Bs4 + (w * 4 + it) * 1024);
    }
    __syncthreads();
#pragma unroll
    for (int kk = 0; kk < 2; ++kk) {
      int4 af[4], bf[4];
#pragma unroll
      for (int mi = 0; mi < 4; ++mi) {
        int r = wm * 64 + mi * 16 + lq;
        af[mi] = As4[r * 8 + ((kk * 4 + quad) ^ (lq & 7))];
      }
#pragma unroll
      for (int ni = 0; ni < 4; ++ni) {
        int r = wn * 64 + ni * 16 + lq;
        bf[ni] = Bs4[r * 8 + ((kk * 4 + quad) ^ (lq & 7))];
      }
#pragma unroll
      for (int mi = 0; mi < 4; ++mi)
#pragma unroll
        for (int ni = 0; ni < 4; ++ni)
          acc[mi][ni] = __builtin_amdgcn_mfma_f32_16x16x32_bf16(
              as_bf(af[mi]), as_bf(bf[ni]), acc[mi][ni], 0, 0, 0);
    }
  }

  if (z < 2) {
    u16* Cout = z ? Kw : Qw;
#pragma unroll
    for (int mi = 0; mi < 4; ++mi)
#pragma unroll
      for (int ni = 0; ni < 4; ++ni)
#pragma unroll
        for (int r = 0; r < 4; ++r) {
          int row = m0 + wm * 64 + mi * 16 + quad * 4 + r;
          int col = n0 + wn * 64 + ni * 16 + lq;
          Cout[(size_t)row * 2048 + col] = f2bf(acc[mi][ni][r] + bias[col]);
        }
  } else {
    // V^T epilogue: BN=256 spans exactly one head (h = blockIdx.x).
    // Two 128-col phases through a 32 KB Ts; 4 waves fill each phase,
    // all 512 threads copy out.
    u16* Ts = (u16*)smem4;
    const int b = m0 >> 10, t0 = m0 & 1023;
    const int h = n0 >> 8;
    const int bh = b * 8 + h;
    const int i4 = tid & 15;
    __syncthreads();  // k-loop LDS reads complete in all waves
#pragma unroll 1
    for (int nh = 0; nh < 2; ++nh) {
      if ((wn >> 1) == nh) {  // waves with wn in {2nh, 2nh+1} own these cols
#pragma unroll
        for (int mi = 0; mi < 4; ++mi)
#pragma unroll
          for (int ni = 0; ni < 4; ++ni) {
            int c = (wn & 1) * 64 + ni * 16 + lq;  // 0..127 within phase
            int r0 = wm * 64 + mi * 16 + quad * 4;
            float vb = bias[n0 + nh * 128 + c];
            uint2 dd;
            dd.x = pkbf(acc[mi][ni][0] + vb, acc[mi][ni][1] + vb);
            dd.y = pkbf(acc[mi][ni][2] + vb, acc[mi][ni][3] + vb);
            *(uint2*)&Ts[c * 128 + (((r0 >> 3) ^ (c & 15)) << 3) + (r0 & 7)] = dd;
          }
      }
      __syncthreads();
#pragma unroll
      for (int cc = 0; cc < 4; ++cc) {
        int c = (tid >> 4) + cc * 32;
        int4 val = *(const int4*)&Ts[c * 128 + ((i4 ^ (c & 15)) << 3)];
        *(int4*)(Vt + (size_t)(bh * 256 + nh * 128 + c) * 1024 + t0 + i4 * 8) =
            val;
      }
      __syncthreads();  // Ts free for next phase
    }
  }
}

// ---------------- out-projection GEMM: BK=128, XCD-swizzled -------------------
// <64,64>, 512 blocks, bijective XCD swizzle (round-7 verified: -7 us);
// BK=128 (round-9: neutral-to-marginal, kept).
template <int BM, int BN>
__global__ __launch_bounds__(256) void gemm_bt(const u16* __restrict__ A,
                                               const u16* __restrict__ Bt,
                                               const float* __restrict__ bias,
                                               float* __restrict__ Cout,
                                               int M, int N, int K) {
  constexpr int BK = 128;
  constexpr int TM = BM / 2 / 16, TN = BN / 2 / 16;
  constexpr int nA = BM / 16, nB = BN / 16;  // 1 KB chunks per wave (4 rows each)
  __shared__ int4 As4[BM * 16];
  __shared__ int4 Bs4[BN * 16];
  const int tid = threadIdx.x;
  const int w = tid >> 6, lane = tid & 63, lq = lane & 15, quad = lane >> 4;
  const int wm = w >> 1, wn = w & 1;
  // bijective XCD swizzle over the 512-block linear grid (4 n-tiles x 128 m)
  const int bid = blockIdx.x;
  const int swz = (bid & 7) * 64 + (bid >> 3);
  const int m0 = (swz >> 2) * BM, n0 = (swz & 3) * BN;

  // staging: chunk j covers rows j*4..j*4+3; source col unit pre-swizzled
  // csrc = (u&8) | ((u&7)^(r&7)) so the read-side XOR recovers linear cols.
  int aoff[nA], boff[nB];
#pragma unroll
  for (int it = 0; it < nA; ++it) {
    int j = w * nA + it;
    int r = j * 4 + (lane >> 4);
    int csrc = (lane & 8) | ((lane & 7) ^ (r & 7));
    aoff[it] = r * K + csrc * 8;
  }
#pragma unroll
  for (int it = 0; it < nB; ++it) {
    int j = w * nB + it;
    int r = j * 4 + (lane >> 4);
    int csrc = (lane & 8) | ((lane & 7) ^ (r & 7));
    boff[it] = r * K + csrc * 8;
  }

  f32x4 acc[TM][TN];
#pragma unroll
  for (int mi = 0; mi < TM; ++mi)
#pragma unroll
    for (int ni = 0; ni < TN; ++ni) {
      f32x4 z4 = {0.f, 0.f, 0.f, 0.f};
      acc[mi][ni] = z4;
    }

  const u16* Abase = A + (size_t)m0 * K;
  const u16* Bbase = Bt + (size_t)n0 * K;

  for (int k0 = 0; k0 < K; k0 += BK) {
    __syncthreads();
#pragma unroll
    for (int it = 0; it < nA; ++it)
      GLDS16(Abase + aoff[it] + k0, (char*)As4 + (w * nA + it) * 1024);
#pragma unroll
    for (int it = 0; it < nB; ++it)
      GLDS16(Bbase + boff[it] + k0, (char*)Bs4 + (w * nB + it) * 1024);
    __syncthreads();
#pragma unroll
    for (int kk = 0; kk < BK / 32; ++kk) {
      int G = kk * 4 + quad;
      int slot = (G >> 3) * 8 + ((G & 7) ^ (lq & 7));
      int4 af[TM], bf[TN];
#pragma unroll
      for (int mi = 0; mi < TM; ++mi) {
        int r = wm * (BM / 2) + mi * 16 + lq;
        af[mi] = As4[r * 16 + slot];
      }
#pragma unroll
      for (int ni = 0; ni < TN; ++ni) {
        int r = wn * (BN / 2) + ni * 16 + lq;
        bf[ni] = Bs4[r * 16 + slot];
      }
#pragma unroll
      for (int mi = 0; mi < TM; ++mi)
#pragma unroll
        for (int ni = 0; ni < TN; ++ni)
          acc[mi][ni] = __builtin_amdgcn_mfma_f32_16x16x32_bf16(
              as_bf(af[mi]), as_bf(bf[ni]), acc[mi][ni], 0, 0, 0);
    }
  }

#pragma unroll
  for (int mi = 0; mi < TM; ++mi)
#pragma unroll
    for (int ni = 0; ni < TN; ++ni)
#pragma unroll
      for (int r = 0; r < 4; ++r) {
        int row = m0 + wm * (BM / 2) + mi * 16 + quad * 4 + r;
        int col = n0 + wn * (BN / 2) + ni * 16 + lq;
        Cout[(size_t)row * N + col] = acc[mi][ni][r] + bias[col];
      }
}

// ---------------- flash attention, strictly causal, S^T form, paired q-tiles ----
// grid (64 bh, 8 pairs); block processes q-tiles {p, 15-p} -> exactly 17 inner
// iterations per block (perfect balance, 512 blocks = 2/CU).
// exp2-domain softmax, finite mask (-3e38), conditional O-rescale, packed cvt.
// (Round-0 verified structure, 74-79 us. Rounds 1/2/5 each restructured it and
// each regressed. Frozen.)
__global__ __launch_bounds__(256, 2) void attn_kernel(const u16* __restrict__ Q,
                                                      const u16* __restrict__ Km,
                                                      const u16* __restrict__ Vt,
                                                      u16* __restrict__ O) {
  const int bh = blockIdx.x;
  const int pair = blockIdx.y;
  const int b = bh >> 3, h = bh & 7;
  const int tid = threadIdx.x;
  const int w = tid >> 6, lane = tid & 63, lq = lane & 15, quad = lane >> 4;

  __shared__ int4 Ks4[2048];   // 64 key-rows x 32 int4 (256 dims), swizzled
  __shared__ int4 Vs4[2048];   // 256 e-rows  x  8 int4 (64 keys), swizzled
  __shared__ u16 Ps[4096];     // per-wave 16x64 P round-trip
  u16* myPs = Ps + w * 1024;

  // staging geometry (global-address-side swizzle), q-tile independent
  int koffb[8], voffb[8];
  {
    const int kg = (lane & 31) >> 3;
#pragma unroll
    for (int it = 0; it < 8; ++it) {
      int r = w * 16 + it * 2 + (lane >> 5);
      int p = (lane & 7) ^ (r & 7);
      koffb[it] = r * 2048 + (kg * 8 + p) * 8;
      int rv = w * 64 + it * 8 + (lane >> 3);
      int cb = (lane & 7) ^ (rv & 7);
      voffb[it] = rv * 1024 + cb * 8;
    }
  }
  const u16* kbase = Km + (size_t)b * 2097152 + h * 256;
  const u16* vbase = Vt + (size_t)bh * 262144;

  const float SCL = 0.09016844f;  // (1/16) * log2(e): softmax in exp2 domain
  const float NEG = -3.0e38f;

#pragma unroll 1
  for (int hv = 0; hv < 2; ++hv) {
    const int qt = hv ? (15 - pair) : pair;
    const int qg = qt * 64 + w * 16 + lq;  // this lane's query index
    const u16* qptr = Q + (size_t)(b * 1024 + qg) * 2048 + h * 256 + quad * 8;
    int4 qf[8];
#pragma unroll
    for (int kk = 0; kk < 8; ++kk) qf[kk] = *(const int4*)(qptr + kk * 32);

    f32x4 of[16];
#pragma unroll
    for (int i = 0; i < 16; ++i) {
      f32x4 z = {0.f, 0.f, 0.f, 0.f};
      of[i] = z;
    }
    float mst = NEG, lst = 0.f;

    for (int kt = 0; kt <= qt; ++kt) {
      __syncthreads();  // prior iter's LDS reads complete
      {
        const u16* kb = kbase + (size_t)kt * 131072;
        const u16* vb = vbase + kt * 64;
#pragma unroll
        for (int it = 0; it < 8; ++it)
          GLDS16(kb + koffb[it], (char*)Ks4 + (w * 8 + it) * 1024);
#pragma unroll
        for (int it = 0; it < 8; ++it)
          GLDS16(vb + voffb[it], (char*)Vs4 + (w * 8 + it) * 1024);
      }
      __syncthreads();  // staged tiles visible

      // ---- S^T = K Q^T : D[key-local][query] ----
      f32x4 sc[4];
#pragma unroll
      for (int ns = 0; ns < 4; ++ns) {
        f32x4 a = {0.f, 0.f, 0.f, 0.f};
        int r = ns * 16 + lq;
#pragma unroll
        for (int kk = 0; kk < 8; ++kk) {
          int G = kk * 4 + quad;
          int4 kf = Ks4[r * 32 + (G >> 3) * 8 + ((G & 7) ^ (lq & 7))];
          a = __builtin_amdgcn_mfma_f32_16x16x32_bf16(as_bf(kf), as_bf(qf[kk]),
                                                      a, 0, 0, 0);
        }
        sc[ns] = a;
      }
      // scale (exp2 domain) + strictly-causal mask (finite NEG)
#pragma unroll
      for (int ns = 0; ns < 4; ++ns) {
        int keyb = kt * 64 + ns * 16 + quad * 4;
#pragma unroll
        for (int r = 0; r < 4; ++r) {
          float v = sc[ns][r] * SCL;
          sc[ns][r] = (keyb + r >= qg) ? NEG : v;
        }
      }
      // online softmax (per lane = per query, reduce across quad groups)
      float m16 = sc[0][0];
#pragma unroll
      for (int ns = 0; ns < 4; ++ns)
#pragma unroll
        for (int r = 0; r < 4; ++r) m16 = fmaxf(m16, sc[ns][r]);
      m16 = fmaxf(m16, __shfl_xor(m16, 16));
      m16 = fmaxf(m16, __shfl_xor(m16, 32));
      if (__any(m16 > mst)) {  // wave-uniform: skip rescale when max unchanged
        float mn = fmaxf(mst, m16);
        float alpha = EXP2(mst - mn);
        mst = mn;
        lst *= alpha;
#pragma unroll
        for (int i = 0; i < 16; ++i)
#pragma unroll
          for (int r = 0; r < 4; ++r) of[i][r] *= alpha;
      }
      float s = 0.f;
#pragma unroll
      for (int ns = 0; ns < 4; ++ns)
#pragma unroll
        for (int r = 0; r < 4; ++r) {
          float p = EXP2(sc[ns][r] - mst);
          sc[ns][r] = p;
          s += p;
        }
      s += __shfl_xor(s, 16);
      s += __shfl_xor(s, 32);
      lst += s;

      // ---- P^T C-layout -> B-layout via per-wave LDS (no barrier) ----
#pragma unroll
      for (int ns = 0; ns < 4; ++ns) {
        int kb2 = ns * 2 + (quad >> 1);
        int base = lq * 64 + ((kb2 ^ (lq & 7)) << 3) + (quad & 1) * 4;
        *(unsigned*)&myPs[base] = pkbf(sc[ns][0], sc[ns][1]);
        *(unsigned*)&myPs[base + 2] = pkbf(sc[ns][2], sc[ns][3]);
      }
      int4 pf[2];
#pragma unroll
      for (int kk2 = 0; kk2 < 2; ++kk2) {
        int kbp = (kk2 * 4 + quad) ^ (lq & 7);
        pf[kk2] = *(const int4*)&myPs[lq * 64 + kbp * 8];
      }
      // ---- O^T += V^T P^T ----
#pragma unroll
      for (int ns2 = 0; ns2 < 16; ++ns2) {
        int r = ns2 * 16 + lq;
#pragma unroll
        for (int kk2 = 0; kk2 < 2; ++kk2) {
          int4 vf = Vs4[r * 8 + ((kk2 * 4 + quad) ^ (lq & 7))];
          of[ns2] = __builtin_amdgcn_mfma_f32_16x16x32_bf16(
              as_bf(vf), as_bf(pf[kk2]), of[ns2], 0, 0, 0);
        }
      }
    }

    float inv = lst > 0.f ? 1.f / lst : 0.f;
    if (qg == 0) inv = 0.f;  // fully-masked first query -> zero row
    u16* optr = O + (size_t)(b * 1024 + qg) * 2048 + h * 256 + quad * 4;
#pragma unroll
    for (int ns2 = 0; ns2 < 16; ++ns2) {
      uint2 o4;
      o4.x = pkbf(of[ns2][0] * inv, of[ns2][1] * inv);
      o4.y = pkbf(of[ns2][2] * inv, of[ns2][3] * inv);
      *(uint2*)(optr + ns2 * 16) = o4;
    }
  }
}

// ---------------- workspace layout (bytes) ----------------
#define WS_XB 0
#define WS_WQT 4194304   /* Wqt|Wkt|Wvt contiguous, 1 MB each */
#define WS_WUT 7340032
#define WS_QW 8388608    /* 32 MB */
#define WS_KW 41943040   /* 32 MB */
#define WS_OW 75497472   /* 32 MB */
#define WS_VTW 109051904 /* 32 MB */

extern "C" void kernel_launch(void* const* d_in, const int* in_sizes, int n_in,
                              void* d_out, int out_size, void* d_ws, size_t ws_size,
                              hipStream_t stream) {
  const float* x = (const float*)d_in[0];
  const float* Wq = (const float*)d_in[1];
  const float* bq = (const float*)d_in[2];
  const float* Wk = (const float*)d_in[3];
  const float* bk = (const float*)d_in[4];
  const float* Wv = (const float*)d_in[5];
  const float* bv = (const float*)d_in[6];
  const float* Wu = (const float*)d_in[7];
  const float* bu = (const float*)d_in[8];
  float* out = (float*)d_out;

  char* ws = (char*)d_ws;
  u16* Xb = (u16*)(ws + WS_XB);
  u16* Wqt = (u16*)(ws + WS_WQT);
  u16* Wkt = Wqt + 524288;
  u16* Wvt = Wqt + 1048576;
  u16* Wut = (u16*)(ws + WS_WUT);
  u16* Qw = (u16*)(ws + WS_QW);
  u16* Kw = (u16*)(ws + WS_KW);
  u16* Ow = (u16*)(ws + WS_OW);
  u16* Vtw = (u16*)(ws + WS_VTW);

  // 1) fused prep: x cast + all weight transposes (one dispatch)
  prep<<<1280, 256, 0, stream>>>(x, Xb, Wq, Wqt, Wk, Wkt, Wv, Wvt, Wu, Wut);

  // 2) fused QKV projections: 128x256 tiles, 8 waves, per-wave 64x64
  //    (1536 blocks, 2 blocks/CU co-resident)
  gemm_qkv<<<dim3(8, 64, 3), 512, 0, stream>>>(Xb, Wqt, bq, bk, bv, Qw, Kw, Vtw);

  // 3) causal flash attention (round-0 verified structure, frozen)
  attn_kernel<<<dim3(64, 8), 256, 0, stream>>>(Qw, Kw, Vtw, Ow);

  // 4) output projection: 64x64 tiles, XCD-swizzled, BK=128
  gemm_bt<64, 64><<<512, 256, 0, stream>>>(Ow, Wut, bu, out, 8192, 256, 2048);
}

// Round 12
// 204.515 us; speedup vs baseline: 1.0774x; 1.0774x over previous
//
#include <hip/hip_runtime.h>
#include <hip/hip_bf16.h>

typedef unsigned short u16;
typedef short bf16x8 __attribute__((ext_vector_type(8)));
typedef float f32x4 __attribute__((ext_vector_type(4)));

// 2^x via raw v_exp_f32 (NOT __exp2f: glibc math.h declares a host __exp2f,
// which collides in hipcc's merged TU)
#define EXP2(x) __builtin_amdgcn_exp2f(x)

static __device__ __forceinline__ u16 f2bf(float f) {
  union { float f; unsigned u; } a; a.f = f;
  unsigned r = a.u + 0x7fffu + ((a.u >> 16) & 1u);  // RNE
  return (u16)(r >> 16);
}

static __device__ __forceinline__ unsigned pkbf(float a, float b) {
  union { __hip_bfloat162 h; unsigned u; } c;
  c.h = __float22bfloat162_rn(make_float2(a, b));
  return c.u;  // low 16 = a, high 16 = b
}

static __device__ __forceinline__ bf16x8 as_bf(int4 v) {
  union { int4 i; bf16x8 b; } u; u.i = v; return u.b;
}

// async global->LDS, 16B per lane; LDS dest = wave-uniform base + lane*16
#define GLDS16(g, l)                                         \
  __builtin_amdgcn_global_load_lds(                          \
      (const __attribute__((address_space(1))) void*)(g),    \
      (__attribute__((address_space(3))) void*)(l), 16, 0, 0)

// ---------------- fused prep: x cast + 4 weight transposes ----------------
// blocks [0,1024): cvt x (fp32->bf16, 8 elems/thread)
// blocks [1024,1280): transpose_w for Wq/Wk/Wv/Wu (64 blocks each)
__global__ __launch_bounds__(256) void prep(
    const float* __restrict__ x, u16* __restrict__ Xb,
    const float* __restrict__ Wq, u16* __restrict__ Wqt,
    const float* __restrict__ Wk, u16* __restrict__ Wkt,
    const float* __restrict__ Wv, u16* __restrict__ Wvt,
    const float* __restrict__ Wu, u16* __restrict__ Wut) {
  const int bid = blockIdx.x, tid = threadIdx.x;
  if (bid < 1024) {
    int i = bid * 256 + tid;
    const float4* p = (const float4*)x + (size_t)i * 2;
    float4 a = p[0], b = p[1];
    union { unsigned s[4]; int4 v; } u2;
    u2.s[0] = pkbf(a.x, a.y); u2.s[1] = pkbf(a.z, a.w);
    u2.s[2] = pkbf(b.x, b.y); u2.s[3] = pkbf(b.z, b.w);
    ((int4*)Xb)[i] = u2.v;
    return;
  }
  const int which = (bid - 1024) >> 6;
  const float* in; u16* out; int R, C;
  if (which == 0)      { in = Wq; out = Wqt; R = 256;  C = 2048; }
  else if (which == 1) { in = Wk; out = Wkt; R = 256;  C = 2048; }
  else if (which == 2) { in = Wv; out = Wvt; R = 256;  C = 2048; }
  else                 { in = Wu; out = Wut; R = 2048; C = 256;  }
  int T = ((bid - 1024) & 63) * 256 + tid;
  int c = T % C;
  int r0 = (T / C) * 32;
  __align__(16) u16 tmp[32];
#pragma unroll
  for (int j = 0; j < 32; ++j) tmp[j] = f2bf(in[(size_t)(r0 + j) * C + c]);
#pragma unroll
  for (int q = 0; q < 4; ++q)
    *(int4*)(out + (size_t)c * R + r0 + q * 8) = *(int4*)&tmp[q * 8];
}

// ---------------- fused QKV GEMM (M=8192,N=2048,K=256, 128x128 tiles) ----------
// (Round-7/9 verified config — qkv's local optimum. Wide-tile variants failed
// twice: r6 BN=256/4-wave (-24 us, occupancy cliff + serialized epilogue) and
// r11 BN=256/8-wave (-12 us, 8-wave barrier spread + coarser scheduling).
// The r8 XCD swizzle also regressed (-8 us: inputs are 7 MB L3-resident, no
// HBM re-fetch to save). 128x128, 256 threads, 3072 blocks stands.)
// z=0 -> Q (row-major bf16), z=1 -> K (row-major), z=2 -> V^T directly
// (LDS tile transpose in the epilogue; no row-major V is ever written).
__global__ __launch_bounds__(256) void gemm_qkv(const u16* __restrict__ A,
                                                const u16* __restrict__ Wt,
                                                const float* __restrict__ bq,
                                                const float* __restrict__ bk,
                                                const float* __restrict__ bv,
                                                u16* __restrict__ Qw,
                                                u16* __restrict__ Kw,
                                                u16* __restrict__ Vt) {
  constexpr int BM = 128, BN = 128, BK = 64;
  __shared__ int4 smem4[2048];  // 32 KB: As(16K) | Bs(16K); reused for transpose
  int4* As4 = smem4;
  int4* Bs4 = smem4 + 1024;
  const int tid = threadIdx.x;
  const int w = tid >> 6, lane = tid & 63, lq = lane & 15, quad = lane >> 4;
  const int wm = w >> 1, wn = w & 1;
  const int m0 = blockIdx.y * BM, n0 = blockIdx.x * BN;
  const int z = blockIdx.z;

  const u16* Btz = Wt + (size_t)z * 2048 * 256;
  const float* bias = (z == 0) ? bq : (z == 1 ? bk : bv);

  const int srow = lane >> 3;
  const int scb = (lane & 7) ^ ((lane >> 3) & 7);

  f32x4 acc[4][4];
#pragma unroll
  for (int mi = 0; mi < 4; ++mi)
#pragma unroll
    for (int ni = 0; ni < 4; ++ni) {
      f32x4 z4 = {0.f, 0.f, 0.f, 0.f};
      acc[mi][ni] = z4;
    }

  for (int k0 = 0; k0 < 256; k0 += BK) {
    __syncthreads();
#pragma unroll
    for (int it = 0; it < 4; ++it) {
      int r = (w * 4 + it) * 8 + srow;
      GLDS16(A + (size_t)(m0 + r) * 256 + k0 + scb * 8,
             (char*)As4 + (w * 4 + it) * 1024);
    }
#pragma unroll
    for (int it = 0; it < 4; ++it) {
      int r = (w * 4 + it) * 8 + srow;
      GLDS16(Btz + (size_t)(n0 + r) * 256 + k0 + scb * 8,
             (char*)Bs4 + (w * 4 + it) * 1024);
    }
    __syncthreads();
#pragma unroll
    for (int kk = 0; kk < 2; ++kk) {
      int4 af[4], bf[4];
#pragma unroll
      for (int mi = 0; mi < 4; ++mi) {
        int r = wm * 64 + mi * 16 + lq;
        af[mi] = As4[r * 8 + ((kk * 4 + quad) ^ (lq & 7))];
      }
#pragma unroll
      for (int ni = 0; ni < 4; ++ni) {
        int r = wn * 64 + ni * 16 + lq;
        bf[ni] = Bs4[r * 8 + ((kk * 4 + quad) ^ (lq & 7))];
      }
#pragma unroll
      for (int mi = 0; mi < 4; ++mi)
#pragma unroll
        for (int ni = 0; ni < 4; ++ni)
          acc[mi][ni] = __builtin_amdgcn_mfma_f32_16x16x32_bf16(
              as_bf(af[mi]), as_bf(bf[ni]), acc[mi][ni], 0, 0, 0);
    }
  }

  if (z < 2) {
    u16* Cout = z ? Kw : Qw;
#pragma unroll
    for (int mi = 0; mi < 4; ++mi)
#pragma unroll
      for (int ni = 0; ni < 4; ++ni)
#pragma unroll
        for (int r = 0; r < 4; ++r) {
          int row = m0 + wm * 64 + mi * 16 + quad * 4 + r;
          int col = n0 + wn * 64 + ni * 16 + lq;
          Cout[(size_t)row * 2048 + col] = f2bf(acc[mi][ni][r] + bias[col]);
        }
  } else {
    // V^T epilogue: transpose the 128x128 tile through LDS, store coalesced.
    __syncthreads();  // all waves done with As4/Bs4
    u16* Ts = (u16*)smem4;
#pragma unroll
    for (int mi = 0; mi < 4; ++mi)
#pragma unroll
      for (int ni = 0; ni < 4; ++ni) {
        int c = wn * 64 + ni * 16 + lq;
        int r0 = wm * 64 + mi * 16 + quad * 4;
        float vb = bias[n0 + c];
        uint2 dd;
        dd.x = pkbf(acc[mi][ni][0] + vb, acc[mi][ni][1] + vb);
        dd.y = pkbf(acc[mi][ni][2] + vb, acc[mi][ni][3] + vb);
        *(uint2*)&Ts[c * 128 + (((r0 >> 3) ^ (c & 15)) << 3) + (r0 & 7)] = dd;
      }
    __syncthreads();
    const int b = m0 >> 10, t0 = m0 & 1023;
    const int e0 = n0 & 255, h = n0 >> 8;
    const int bh = b * 8 + h;
    const int i4 = tid & 15;
#pragma unroll
    for (int cc = 0; cc < 8; ++cc) {
      int c = (tid >> 4) + cc * 16;
      int4 val = *(const int4*)&Ts[c * 128 + ((i4 ^ (c & 15)) << 3)];
      *(int4*)(Vt + (size_t)(bh * 256 + e0 + c) * 1024 + t0 + i4 * 8) = val;
    }
  }
}

// ---------------- out-projection GEMM: BK=128, XCD-swizzled -------------------
// <64,64>, 512 blocks, bijective XCD swizzle (round-7 verified: -7 us — the 4
// column-blocks sharing a 256 KB A-slice co-locate per XCD, A fetched once);
// BK=128 (round-9 verified: neutral-to-marginal vs BK=64, kept).
template <int BM, int BN>
__global__ __launch_bounds__(256) void gemm_bt(const u16* __restrict__ A,
                                               const u16* __restrict__ Bt,
                                               const float* __restrict__ bias,
                                               float* __restrict__ Cout,
                                               int M, int N, int K) {
  constexpr int BK = 128;
  constexpr int TM = BM / 2 / 16, TN = BN / 2 / 16;
  constexpr int nA = BM / 16, nB = BN / 16;  // 1 KB chunks per wave (4 rows each)
  __shared__ int4 As4[BM * 16];
  __shared__ int4 Bs4[BN * 16];
  const int tid = threadIdx.x;
  const int w = tid >> 6, lane = tid & 63, lq = lane & 15, quad = lane >> 4;
  const int wm = w >> 1, wn = w & 1;
  // bijective XCD swizzle over the 512-block linear grid (4 n-tiles x 128 m)
  const int bid = blockIdx.x;
  const int swz = (bid & 7) * 64 + (bid >> 3);
  const int m0 = (swz >> 2) * BM, n0 = (swz & 3) * BN;

  // staging: chunk j covers rows j*4..j*4+3; source col unit pre-swizzled
  // csrc = (u&8) | ((u&7)^(r&7)) so the read-side XOR recovers linear cols.
  int aoff[nA], boff[nB];
#pragma unroll
  for (int it = 0; it < nA; ++it) {
    int j = w * nA + it;
    int r = j * 4 + (lane >> 4);
    int csrc = (lane & 8) | ((lane & 7) ^ (r & 7));
    aoff[it] = r * K + csrc * 8;
  }
#pragma unroll
  for (int it = 0; it < nB; ++it) {
    int j = w * nB + it;
    int r = j * 4 + (lane >> 4);
    int csrc = (lane & 8) | ((lane & 7) ^ (r & 7));
    boff[it] = r * K + csrc * 8;
  }

  f32x4 acc[TM][TN];
#pragma unroll
  for (int mi = 0; mi < TM; ++mi)
#pragma unroll
    for (int ni = 0; ni < TN; ++ni) {
      f32x4 z4 = {0.f, 0.f, 0.f, 0.f};
      acc[mi][ni] = z4;
    }

  const u16* Abase = A + (size_t)m0 * K;
  const u16* Bbase = Bt + (size_t)n0 * K;

  for (int k0 = 0; k0 < K; k0 += BK) {
    __syncthreads();
#pragma unroll
    for (int it = 0; it < nA; ++it)
      GLDS16(Abase + aoff[it] + k0, (char*)As4 + (w * nA + it) * 1024);
#pragma unroll
    for (int it = 0; it < nB; ++it)
      GLDS16(Bbase + boff[it] + k0, (char*)Bs4 + (w * nB + it) * 1024);
    __syncthreads();
#pragma unroll
    for (int kk = 0; kk < BK / 32; ++kk) {
      int G = kk * 4 + quad;
      int slot = (G >> 3) * 8 + ((G & 7) ^ (lq & 7));
      int4 af[TM], bf[TN];
#pragma unroll
      for (int mi = 0; mi < TM; ++mi) {
        int r = wm * (BM / 2) + mi * 16 + lq;
        af[mi] = As4[r * 16 + slot];
      }
#pragma unroll
      for (int ni = 0; ni < TN; ++ni) {
        int r = wn * (BN / 2) + ni * 16 + lq;
        bf[ni] = Bs4[r * 16 + slot];
      }
#pragma unroll
      for (int mi = 0; mi < TM; ++mi)
#pragma unroll
        for (int ni = 0; ni < TN; ++ni)
          acc[mi][ni] = __builtin_amdgcn_mfma_f32_16x16x32_bf16(
              as_bf(af[mi]), as_bf(bf[ni]), acc[mi][ni], 0, 0, 0);
    }
  }

#pragma unroll
  for (int mi = 0; mi < TM; ++mi)
#pragma unroll
    for (int ni = 0; ni < TN; ++ni)
#pragma unroll
      for (int r = 0; r < 4; ++r) {
        int row = m0 + wm * (BM / 2) + mi * 16 + quad * 4 + r;
        int col = n0 + wn * (BN / 2) + ni * 16 + lq;
        Cout[(size_t)row * N + col] = acc[mi][ni][r] + bias[col];
      }
}

// ---------------- flash attention, strictly causal, S^T form, paired q-tiles ----
// grid (64 bh, 8 pairs); block processes q-tiles {p, 15-p} -> exactly 17 inner
// iterations per block (perfect balance, 512 blocks = 2/CU).
// exp2-domain softmax, finite mask (-3e38), conditional O-rescale, packed cvt.
// (Round-0 verified structure, 74-79 us. Rounds 1/2/5 each restructured it and
// each regressed: its invariants — uniform per-block work, 2 co-resident
// blocks/CU, 64-key tiles amortizing the per-iter softmax chain — are
// load-bearing. Frozen.)
__global__ __launch_bounds__(256, 2) void attn_kernel(const u16* __restrict__ Q,
                                                      const u16* __restrict__ Km,
                                                      const u16* __restrict__ Vt,
                                                      u16* __restrict__ O) {
  const int bh = blockIdx.x;
  const int pair = blockIdx.y;
  const int b = bh >> 3, h = bh & 7;
  const int tid = threadIdx.x;
  const int w = tid >> 6, lane = tid & 63, lq = lane & 15, quad = lane >> 4;

  __shared__ int4 Ks4[2048];   // 64 key-rows x 32 int4 (256 dims), swizzled
  __shared__ int4 Vs4[2048];   // 256 e-rows  x  8 int4 (64 keys), swizzled
  __shared__ u16 Ps[4096];     // per-wave 16x64 P round-trip
  u16* myPs = Ps + w * 1024;

  // staging geometry (global-address-side swizzle), q-tile independent
  int koffb[8], voffb[8];
  {
    const int kg = (lane & 31) >> 3;
#pragma unroll
    for (int it = 0; it < 8; ++it) {
      int r = w * 16 + it * 2 + (lane >> 5);
      int p = (lane & 7) ^ (r & 7);
      koffb[it] = r * 2048 + (kg * 8 + p) * 8;
      int rv = w * 64 + it * 8 + (lane >> 3);
      int cb = (lane & 7) ^ (rv & 7);
      voffb[it] = rv * 1024 + cb * 8;
    }
  }
  const u16* kbase = Km + (size_t)b * 2097152 + h * 256;
  const u16* vbase = Vt + (size_t)bh * 262144;

  const float SCL = 0.09016844f;  // (1/16) * log2(e): softmax in exp2 domain
  const float NEG = -3.0e38f;

#pragma unroll 1
  for (int hv = 0; hv < 2; ++hv) {
    const int qt = hv ? (15 - pair) : pair;
    const int qg = qt * 64 + w * 16 + lq;  // this lane's query index
    const u16* qptr = Q + (size_t)(b * 1024 + qg) * 2048 + h * 256 + quad * 8;
    int4 qf[8];
#pragma unroll
    for (int kk = 0; kk < 8; ++kk) qf[kk] = *(const int4*)(qptr + kk * 32);

    f32x4 of[16];
#pragma unroll
    for (int i = 0; i < 16; ++i) {
      f32x4 z = {0.f, 0.f, 0.f, 0.f};
      of[i] = z;
    }
    float mst = NEG, lst = 0.f;

    for (int kt = 0; kt <= qt; ++kt) {
      __syncthreads();  // prior iter's LDS reads complete
      {
        const u16* kb = kbase + (size_t)kt * 131072;
        const u16* vb = vbase + kt * 64;
#pragma unroll
        for (int it = 0; it < 8; ++it)
          GLDS16(kb + koffb[it], (char*)Ks4 + (w * 8 + it) * 1024);
#pragma unroll
        for (int it = 0; it < 8; ++it)
          GLDS16(vb + voffb[it], (char*)Vs4 + (w * 8 + it) * 1024);
      }
      __syncthreads();  // staged tiles visible

      // ---- S^T = K Q^T : D[key-local][query] ----
      f32x4 sc[4];
#pragma unroll
      for (int ns = 0; ns < 4; ++ns) {
        f32x4 a = {0.f, 0.f, 0.f, 0.f};
        int r = ns * 16 + lq;
#pragma unroll
        for (int kk = 0; kk < 8; ++kk) {
          int G = kk * 4 + quad;
          int4 kf = Ks4[r * 32 + (G >> 3) * 8 + ((G & 7) ^ (lq & 7))];
          a = __builtin_amdgcn_mfma_f32_16x16x32_bf16(as_bf(kf), as_bf(qf[kk]),
                                                      a, 0, 0, 0);
        }
        sc[ns] = a;
      }
      // scale (exp2 domain) + strictly-causal mask (finite NEG)
#pragma unroll
      for (int ns = 0; ns < 4; ++ns) {
        int keyb = kt * 64 + ns * 16 + quad * 4;
#pragma unroll
        for (int r = 0; r < 4; ++r) {
          float v = sc[ns][r] * SCL;
          sc[ns][r] = (keyb + r >= qg) ? NEG : v;
        }
      }
      // online softmax (per lane = per query, reduce across quad groups)
      float m16 = sc[0][0];
#pragma unroll
      for (int ns = 0; ns < 4; ++ns)
#pragma unroll
        for (int r = 0; r < 4; ++r) m16 = fmaxf(m16, sc[ns][r]);
      m16 = fmaxf(m16, __shfl_xor(m16, 16));
      m16 = fmaxf(m16, __shfl_xor(m16, 32));
      if (__any(m16 > mst)) {  // wave-uniform: skip rescale when max unchanged
        float mn = fmaxf(mst, m16);
        float alpha = EXP2(mst - mn);
        mst = mn;
        lst *= alpha;
#pragma unroll
        for (int i = 0; i < 16; ++i)
#pragma unroll
          for (int r = 0; r < 4; ++r) of[i][r] *= alpha;
      }
      float s = 0.f;
#pragma unroll
      for (int ns = 0; ns < 4; ++ns)
#pragma unroll
        for (int r = 0; r < 4; ++r) {
          float p = EXP2(sc[ns][r] - mst);
          sc[ns][r] = p;
          s += p;
        }
      s += __shfl_xor(s, 16);
      s += __shfl_xor(s, 32);
      lst += s;

      // ---- P^T C-layout -> B-layout via per-wave LDS (no barrier) ----
#pragma unroll
      for (int ns = 0; ns < 4; ++ns) {
        int kb2 = ns * 2 + (quad >> 1);
        int base = lq * 64 + ((kb2 ^ (lq & 7)) << 3) + (quad & 1) * 4;
        *(unsigned*)&myPs[base] = pkbf(sc[ns][0], sc[ns][1]);
        *(unsigned*)&myPs[base + 2] = pkbf(sc[ns][2], sc[ns][3]);
      }
      int4 pf[2];
#pragma unroll
      for (int kk2 = 0; kk2 < 2; ++kk2) {
        int kbp = (kk2 * 4 + quad) ^ (lq & 7);
        pf[kk2] = *(const int4*)&myPs[lq * 64 + kbp * 8];
      }
      // ---- O^T += V^T P^T ----
#pragma unroll
      for (int ns2 = 0; ns2 < 16; ++ns2) {
        int r = ns2 * 16 + lq;
#pragma unroll
        for (int kk2 = 0; kk2 < 2; ++kk2) {
          int4 vf = Vs4[r * 8 + ((kk2 * 4 + quad) ^ (lq & 7))];
          of[ns2] = __builtin_amdgcn_mfma_f32_16x16x32_bf16(
              as_bf(vf), as_bf(pf[kk2]), of[ns2], 0, 0, 0);
        }
      }
    }

    float inv = lst > 0.f ? 1.f / lst : 0.f;
    if (qg == 0) inv = 0.f;  // fully-masked first query -> zero row
    u16* optr = O + (size_t)(b * 1024 + qg) * 2048 + h * 256 + quad * 4;
#pragma unroll
    for (int ns2 = 0; ns2 < 16; ++ns2) {
      uint2 o4;
      o4.x = pkbf(of[ns2][0] * inv, of[ns2][1] * inv);
      o4.y = pkbf(of[ns2][2] * inv, of[ns2][3] * inv);
      *(uint2*)(optr + ns2 * 16) = o4;
    }
  }
}

// ---------------- workspace layout (bytes) ----------------
#define WS_XB 0
#define WS_WQT 4194304   /* Wqt|Wkt|Wvt contiguous, 1 MB each */
#define WS_WUT 7340032
#define WS_QW 8388608    /* 32 MB */
#define WS_KW 41943040   /* 32 MB */
#define WS_OW 75497472   /* 32 MB */
#define WS_VTW 109051904 /* 32 MB */

extern "C" void kernel_launch(void* const* d_in, const int* in_sizes, int n_in,
                              void* d_out, int out_size, void* d_ws, size_t ws_size,
                              hipStream_t stream) {
  const float* x = (const float*)d_in[0];
  const float* Wq = (const float*)d_in[1];
  const float* bq = (const float*)d_in[2];
  const float* Wk = (const float*)d_in[3];
  const float* bk = (const float*)d_in[4];
  const float* Wv = (const float*)d_in[5];
  const float* bv = (const float*)d_in[6];
  const float* Wu = (const float*)d_in[7];
  const float* bu = (const float*)d_in[8];
  float* out = (float*)d_out;

  char* ws = (char*)d_ws;
  u16* Xb = (u16*)(ws + WS_XB);
  u16* Wqt = (u16*)(ws + WS_WQT);
  u16* Wkt = Wqt + 524288;
  u16* Wvt = Wqt + 1048576;
  u16* Wut = (u16*)(ws + WS_WUT);
  u16* Qw = (u16*)(ws + WS_QW);
  u16* Kw = (u16*)(ws + WS_KW);
  u16* Ow = (u16*)(ws + WS_OW);
  u16* Vtw = (u16*)(ws + WS_VTW);

  // 1) fused prep: x cast + all weight transposes (one dispatch)
  prep<<<1280, 256, 0, stream>>>(x, Xb, Wq, Wqt, Wk, Wkt, Wv, Wvt, Wu, Wut);

  // 2) fused QKV projections, 128x128 tiles (verified local optimum)
  gemm_qkv<<<dim3(16, 64, 3), 256, 0, stream>>>(Xb, Wqt, bq, bk, bv, Qw, Kw, Vtw);

  // 3) causal flash attention (round-0 verified structure, frozen)
  attn_kernel<<<dim3(64, 8), 256, 0, stream>>>(Qw, Kw, Vtw, Ow);

  // 4) output projection: 64x64 tiles, XCD-swizzled, BK=128
  gemm_bt<64, 64><<<512, 256, 0, stream>>>(Ow, Wut, bu, out, 8192, 256, 2048);
}